// Round 1
// baseline (1646.755 us; speedup 1.0000x reference)
//
#include <hip/hip_runtime.h>
#include <math.h>

// ---------------------------------------------------------------------------
// SALAD forward, fp32 baseline.
// Shapes: B=64, C=768, N=1024 (=32*32), HID=512, L=128, M=64, G=256.
// ---------------------------------------------------------------------------

#define B_SZ   64
#define C_IN   768
#define N_LOC  1024
#define HID    512
#define L_DIM  128
#define M_DIM  64
#define G_DIM  256

__device__ __forceinline__ float waveReduceSum(float v) {
#pragma unroll
    for (int off = 32; off > 0; off >>= 1) v += __shfl_xor(v, off, 64);
    return v;
}

// ---------------------------------------------------------------------------
// GEMM: C[b,m,n] = act( sum_k W[m,k] * X[b,k,n] + bias[m] )
// Tile 128x128, BK=8, 256 threads, 8x8 micro-tile per thread.
// grid = (N/128, ceil(M/128), B)
// ---------------------------------------------------------------------------
template <bool RELU>
__global__ __launch_bounds__(256) void gemm_wx(const float* __restrict__ W,
                                               const float* __restrict__ X,
                                               const float* __restrict__ bias,
                                               float* __restrict__ C,
                                               int M, int K, int N) {
    __shared__ __align__(16) float As[8][128];  // As[k][m]
    __shared__ __align__(16) float Bs[8][128];  // Bs[k][n]
    const int tid = threadIdx.x;
    const int tx = tid & 15;   // -> n micro
    const int ty = tid >> 4;   // -> m micro
    const int m0 = blockIdx.y * 128;
    const int n0 = blockIdx.x * 128;
    const float* Xb = X + (size_t)blockIdx.z * K * N;
    float* Cb = C + (size_t)blockIdx.z * M * N;

    const int am = tid >> 1;          // 0..127 : m within tile
    const int ak = (tid & 1) << 2;    // 0 or 4 : k within chunk
    const int bk = tid >> 5;          // 0..7   : k within chunk
    const int bn = (tid & 31) << 2;   // 0..124 : n within tile

    float acc[8][8] = {};

    for (int k0 = 0; k0 < K; k0 += 8) {
        float4 av;
        if (m0 + am < M)
            av = *(const float4*)(W + (size_t)(m0 + am) * K + k0 + ak);
        else
            av = make_float4(0.f, 0.f, 0.f, 0.f);
        float4 bv = *(const float4*)(Xb + (size_t)(k0 + bk) * N + n0 + bn);
        As[ak + 0][am] = av.x;
        As[ak + 1][am] = av.y;
        As[ak + 2][am] = av.z;
        As[ak + 3][am] = av.w;
        *(float4*)(&Bs[bk][bn]) = bv;
        __syncthreads();
#pragma unroll
        for (int k = 0; k < 8; ++k) {
            float4 a01 = *(const float4*)(&As[k][ty * 8]);
            float4 a23 = *(const float4*)(&As[k][ty * 8 + 4]);
            float4 b01 = *(const float4*)(&Bs[k][tx * 8]);
            float4 b23 = *(const float4*)(&Bs[k][tx * 8 + 4]);
            float a[8] = {a01.x, a01.y, a01.z, a01.w, a23.x, a23.y, a23.z, a23.w};
            float b[8] = {b01.x, b01.y, b01.z, b01.w, b23.x, b23.y, b23.z, b23.w};
#pragma unroll
            for (int i = 0; i < 8; ++i)
#pragma unroll
                for (int j = 0; j < 8; ++j)
                    acc[i][j] = fmaf(a[i], b[j], acc[i][j]);
        }
        __syncthreads();
    }

#pragma unroll
    for (int i = 0; i < 8; ++i) {
        const int gm = m0 + ty * 8 + i;
        if (gm >= M) break;
        const float bsv = bias[gm];
        float o[8];
#pragma unroll
        for (int j = 0; j < 8; ++j) {
            float v = acc[i][j] + bsv;
            if (RELU) v = fmaxf(v, 0.f);
            o[j] = v;
        }
        float* dst = Cb + (size_t)gm * N + n0 + tx * 8;
        *(float4*)(dst + 0) = make_float4(o[0], o[1], o[2], o[3]);
        *(float4*)(dst + 4) = make_float4(o[4], o[5], o[6], o[7]);
    }
}

// ---------------------------------------------------------------------------
// Token MLP: tok[b,g] = (relu(t @ tw1^T + tb1) @ tw2^T + tb2)[g]
// One block per batch, 256 threads (4 waves), wave-per-output-row dots.
// ---------------------------------------------------------------------------
__global__ __launch_bounds__(256) void tok_kernel(const float* __restrict__ t,
                                                  const float* __restrict__ tw1,
                                                  const float* __restrict__ tb1,
                                                  const float* __restrict__ tw2,
                                                  const float* __restrict__ tb2,
                                                  float* __restrict__ tok) {
    __shared__ __align__(16) float tl[C_IN];
    __shared__ __align__(16) float hid[HID];
    const int b = blockIdx.x;
    const int tid = threadIdx.x;
    const int lane = tid & 63;
    const int wave = tid >> 6;

    for (int i = tid; i < C_IN; i += 256) tl[i] = t[(size_t)b * C_IN + i];
    __syncthreads();

    // stage 1: 512 rows, dot over 768
    for (int j = wave; j < HID; j += 4) {
        const float4* wr = (const float4*)(tw1 + (size_t)j * C_IN);
        const float4* tr = (const float4*)tl;
        float s = 0.f;
#pragma unroll
        for (int q = 0; q < 3; ++q) {
            float4 wv = wr[lane + 64 * q];
            float4 tv = tr[lane + 64 * q];
            s += wv.x * tv.x + wv.y * tv.y + wv.z * tv.z + wv.w * tv.w;
        }
        s = waveReduceSum(s);
        if (lane == 0) hid[j] = fmaxf(s + tb1[j], 0.f);
    }
    __syncthreads();

    // stage 2: 256 rows, dot over 512
    for (int g = wave; g < G_DIM; g += 4) {
        const float4* wr = (const float4*)(tw2 + (size_t)g * HID);
        const float4* hr = (const float4*)hid;
        float s = 0.f;
#pragma unroll
        for (int q = 0; q < 2; ++q) {
            float4 wv = wr[lane + 64 * q];
            float4 hv = hr[lane + 64 * q];
            s += wv.x * hv.x + wv.y * hv.y + wv.z * hv.z + wv.w * hv.w;
        }
        s = waveReduceSum(s);
        if (lane == 0) tok[(size_t)b * G_DIM + g] = s + tb2[g];
    }
}

// ---------------------------------------------------------------------------
// Sinkhorn (3 iters) + P = exp(Z+u+v-norm), rows 0..63.
// One block (1024 threads) per batch; thread t owns column t.
// Z[m][n] = p[b,m,n] for m<64, = alpha for m==64 (dust bin).
// No max-subtraction in logsumexp: all arguments bounded (|Z+u+v| < ~20).
// ---------------------------------------------------------------------------
__global__ __launch_bounds__(1024) void sinkhorn_kernel(const float* __restrict__ p,
                                                        const float* __restrict__ dust,
                                                        float* __restrict__ P) {
    __shared__ float u[M_DIM + 1];
    __shared__ float v[N_LOC];
    const int b = blockIdx.x;
    const int t = threadIdx.x;
    const int lane = t & 63;
    const int wave = t >> 6;
    const float alpha = dust[0];
    const float norm = -__logf(1088.f);                 // -log(m+n), m=64 n=1024
    const float logmu_main = norm;
    const float logmu_last = __logf(960.f) + norm;      // log(n-m)+norm
    const float lognu = norm;
    const float* pb = p + (size_t)b * M_DIM * N_LOC;

    v[t] = 0.f;
    if (t < M_DIM + 1) u[t] = 0.f;
    __syncthreads();

    for (int it = 0; it < 3; ++it) {
        // u[m] = log_mu[m] - log sum_n exp(Z[m,n] + v[n]); wave w does rows w, w+16, ...
        for (int m = wave; m < M_DIM + 1; m += 16) {
            float s = 0.f;
            if (m < M_DIM) {
                const float* row = pb + (size_t)m * N_LOC;
#pragma unroll
                for (int q = 0; q < 16; ++q) {
                    int c = lane + 64 * q;
                    s += __expf(row[c] + v[c]);
                }
            } else {
#pragma unroll
                for (int q = 0; q < 16; ++q) {
                    int c = lane + 64 * q;
                    s += __expf(alpha + v[c]);
                }
            }
            s = waveReduceSum(s);
            if (lane == 0) u[m] = ((m < M_DIM) ? logmu_main : logmu_last) - __logf(s);
        }
        __syncthreads();
        // v[n] = log_nu - log sum_m exp(Z[m,n] + u[m])
        float s = 0.f;
        for (int m = 0; m < M_DIM; ++m) s += __expf(pb[(size_t)m * N_LOC + t] + u[m]);
        s += __expf(alpha + u[M_DIM]);
        v[t] = lognu - __logf(s);
        __syncthreads();
    }

    const float vt = v[t];
    float* Pb = P + (size_t)b * M_DIM * N_LOC;
    for (int m = 0; m < M_DIM; ++m)
        Pb[(size_t)m * N_LOC + t] = __expf(pb[(size_t)m * N_LOC + t] + u[m] + vt - norm);
}

// ---------------------------------------------------------------------------
// agg[b,l,m] = sum_n f[b,l,n] * P[b,m,n].   One block (512 thr) per batch.
// n-chunks of 64 staged in LDS (transposed), 4x4 micro-tile per thread.
// ---------------------------------------------------------------------------
__global__ __launch_bounds__(512) void agg_kernel(const float* __restrict__ f,
                                                  const float* __restrict__ P,
                                                  float* __restrict__ agg) {
    __shared__ __align__(16) float Fs[64][L_DIM];  // Fs[nn][l]
    __shared__ __align__(16) float Ps[64][M_DIM];  // Ps[nn][m]
    const int b = blockIdx.x;
    const int tid = threadIdx.x;
    const float* fb = f + (size_t)b * L_DIM * N_LOC;
    const float* Pb = P + (size_t)b * M_DIM * N_LOC;
    const int m0 = (tid & 15) * 4;
    const int l0 = (tid >> 4) * 4;

    const int fl = tid & 127;
    const int fn = (tid >> 7) * 4;
    const int pm = tid & 63;
    const int pn = (tid >> 6) * 4;

    float acc[4][4] = {};

    for (int n0 = 0; n0 < N_LOC; n0 += 64) {
        __syncthreads();
#pragma unroll
        for (int pass = 0; pass < 4; ++pass) {
            int nn = fn + pass * 16;
            float4 vv = *(const float4*)(fb + (size_t)fl * N_LOC + n0 + nn);
            Fs[nn + 0][fl] = vv.x;
            Fs[nn + 1][fl] = vv.y;
            Fs[nn + 2][fl] = vv.z;
            Fs[nn + 3][fl] = vv.w;
        }
#pragma unroll
        for (int pass = 0; pass < 2; ++pass) {
            int nn = pn + pass * 32;
            float4 vv = *(const float4*)(Pb + (size_t)pm * N_LOC + n0 + nn);
            Ps[nn + 0][pm] = vv.x;
            Ps[nn + 1][pm] = vv.y;
            Ps[nn + 2][pm] = vv.z;
            Ps[nn + 3][pm] = vv.w;
        }
        __syncthreads();
#pragma unroll 8
        for (int nn = 0; nn < 64; ++nn) {
            float4 a = *(const float4*)(&Fs[nn][l0]);
            float4 bb = *(const float4*)(&Ps[nn][m0]);
            float av[4] = {a.x, a.y, a.z, a.w};
            float bv[4] = {bb.x, bb.y, bb.z, bb.w};
#pragma unroll
            for (int i = 0; i < 4; ++i)
#pragma unroll
                for (int j = 0; j < 4; ++j)
                    acc[i][j] = fmaf(av[i], bv[j], acc[i][j]);
        }
    }

#pragma unroll
    for (int i = 0; i < 4; ++i) {
        float* dst = agg + ((size_t)b * L_DIM + l0 + i) * M_DIM + m0;
        *(float4*)dst = make_float4(acc[i][0], acc[i][1], acc[i][2], acc[i][3]);
    }
}

// ---------------------------------------------------------------------------
// Final: per-m intra-norm of agg (over l), tok norm, concat, global L2 norm.
// One block (256 thr) per batch. out[b, 0:256]=tokN, out[b, 256+l*64+m]=aggN.
// ---------------------------------------------------------------------------
__global__ __launch_bounds__(256) void final_kernel(const float* __restrict__ agg,
                                                    const float* __restrict__ tok,
                                                    float* __restrict__ out) {
    __shared__ __align__(16) float ag[L_DIM * M_DIM];  // 8192 floats
    __shared__ float rm[M_DIM];
    __shared__ float red[4];
    __shared__ float tk[G_DIM];
    const int b = blockIdx.x;
    const int tid = threadIdx.x;
    const int lane = tid & 63;
    const int wave = tid >> 6;
    const float EPS = 1e-12f;

    const float4* ab = (const float4*)(agg + (size_t)b * L_DIM * M_DIM);
    for (int e4 = tid; e4 < L_DIM * M_DIM / 4; e4 += 256) ((float4*)ag)[e4] = ab[e4];
    tk[tid] = tok[(size_t)b * G_DIM + tid];
    __syncthreads();

    // per-m norms over l
    if (tid < M_DIM) {
        float ss = 0.f;
#pragma unroll 8
        for (int l = 0; l < L_DIM; ++l) {
            float x = ag[l * M_DIM + tid];
            ss = fmaf(x, x, ss);
        }
        rm[tid] = 1.f / fmaxf(sqrtf(ss), EPS);
    }
    // tok sumsq
    const float tv = tk[tid];
    float ssl = tv * tv;
    ssl = waveReduceSum(ssl);
    if (lane == 0) red[wave] = ssl;
    __syncthreads();
    const float stok = red[0] + red[1] + red[2] + red[3];
    const float rt = 1.f / fmaxf(sqrtf(stok), EPS);
    const float tn = tv * rt;

    // global sumsq over normalized concat vector
    float gs = tn * tn;
    for (int e = tid; e < L_DIM * M_DIM; e += 256) {
        float x = ag[e] * rm[e & (M_DIM - 1)];
        gs = fmaf(x, x, gs);
    }
    __syncthreads();  // red reuse
    gs = waveReduceSum(gs);
    if (lane == 0) red[wave] = gs;
    __syncthreads();
    const float G = red[0] + red[1] + red[2] + red[3];
    const float rg = 1.f / fmaxf(sqrtf(G), EPS);

    float* ob = out + (size_t)b * (G_DIM + L_DIM * M_DIM);
    ob[tid] = tn * rg;
    for (int e = tid; e < L_DIM * M_DIM; e += 256)
        ob[G_DIM + e] = ag[e] * rm[e & (M_DIM - 1)] * rg;
}

// ---------------------------------------------------------------------------
extern "C" void kernel_launch(void* const* d_in, const int* in_sizes, int n_in,
                              void* d_out, int out_size, void* d_ws, size_t ws_size,
                              hipStream_t stream) {
    const float* x    = (const float*)d_in[0];
    const float* t    = (const float*)d_in[1];
    const float* tw1  = (const float*)d_in[2];
    const float* tb1  = (const float*)d_in[3];
    const float* tw2  = (const float*)d_in[4];
    const float* tb2  = (const float*)d_in[5];
    const float* cw1  = (const float*)d_in[6];
    const float* cb1  = (const float*)d_in[7];
    const float* cw2  = (const float*)d_in[8];
    const float* cb2  = (const float*)d_in[9];
    const float* sw1  = (const float*)d_in[10];
    const float* sb1  = (const float*)d_in[11];
    const float* sw2  = (const float*)d_in[12];
    const float* sb2  = (const float*)d_in[13];
    const float* dust = (const float*)d_in[14];
    float* out = (float*)d_out;

    char* ws = (char*)d_ws;
    const size_t szH   = (size_t)B_SZ * HID * N_LOC * 4;      // 134,217,728
    const size_t szF   = (size_t)B_SZ * L_DIM * N_LOC * 4;    //  33,554,432
    const size_t szP   = (size_t)B_SZ * M_DIM * N_LOC * 4;    //  16,777,216
    const size_t szTok = (size_t)B_SZ * G_DIM * 4;            //      65,536
    float* hbuf   = (float*)(ws);
    float* fbuf   = (float*)(ws + szH);
    float* pbuf   = (float*)(ws + szH + szF);
    float* Pbuf   = (float*)(ws + szH + szF + szP);
    float* tokbuf = (float*)(ws + szH + szF + szP + szP);
    float* aggbuf = (float*)(ws + szH + szF + szP + szP + szTok);

    // h = relu(cw1 @ x + cb1)            [B,512,1024]
    gemm_wx<true><<<dim3(8, 4, B_SZ), 256, 0, stream>>>(cw1, x, cb1, hbuf, HID, C_IN, N_LOC);
    // f = cw2 @ h + cb2                  [B,128,1024]
    gemm_wx<false><<<dim3(8, 1, B_SZ), 256, 0, stream>>>(cw2, hbuf, cb2, fbuf, L_DIM, HID, N_LOC);
    // s = relu(sw1 @ x + sb1)            [B,512,1024]  (reuses hbuf)
    gemm_wx<true><<<dim3(8, 4, B_SZ), 256, 0, stream>>>(sw1, x, sb1, hbuf, HID, C_IN, N_LOC);
    // p = sw2 @ s + sb2                  [B,64,1024]
    gemm_wx<false><<<dim3(8, 1, B_SZ), 256, 0, stream>>>(sw2, hbuf, sb2, pbuf, M_DIM, HID, N_LOC);
    // token MLP
    tok_kernel<<<B_SZ, 256, 0, stream>>>(t, tw1, tb1, tw2, tb2, tokbuf);
    // Sinkhorn + exp
    sinkhorn_kernel<<<B_SZ, 1024, 0, stream>>>(pbuf, dust, Pbuf);
    // VLAD aggregation
    agg_kernel<<<B_SZ, 512, 0, stream>>>(fbuf, Pbuf, aggbuf);
    // normalization cascade + output
    final_kernel<<<B_SZ, 256, 0, stream>>>(aggbuf, tokbuf, out);
}

// Round 2
// 566.935 us; speedup vs baseline: 2.9047x; 2.9047x over previous
//
#include <hip/hip_runtime.h>
#include <math.h>

// ---------------------------------------------------------------------------
// SALAD forward, bf16-MFMA version.
// Everything location-major ("transposed"): xT[B][N][C], hT[B][N][HID],
// fT[B][N][L], pT[B][N][M].  GEMMs: C'[n][s] = sum_k X'[n][k] * W[s][k].
// Shapes: B=64, C=768, N=1024, HID=512, L=128, M=64, G=256.
// ---------------------------------------------------------------------------

#define B_SZ   64
#define C_IN   768
#define N_LOC  1024
#define HID    512
#define L_DIM  128
#define M_DIM  64
#define G_DIM  256

typedef unsigned short u16;
typedef __bf16 bf16x8 __attribute__((ext_vector_type(8)));
typedef float f32x4 __attribute__((ext_vector_type(4)));

typedef const __attribute__((address_space(1))) void* gptr_t;
typedef __attribute__((address_space(3))) void* sptr_t;

__device__ __forceinline__ void load_lds16(const void* g, void* l) {
    __builtin_amdgcn_global_load_lds((gptr_t)g, (sptr_t)l, 16, 0, 0);
}

__device__ __forceinline__ u16 f2bf(float f) {  // round-to-nearest-even
    unsigned u = __float_as_uint(f);
    u += 0x7fffu + ((u >> 16) & 1u);
    return (u16)(u >> 16);
}
__device__ __forceinline__ float bf2f(u16 h) {
    return __uint_as_float(((unsigned)h) << 16);
}

__device__ __forceinline__ float waveReduceSum(float v) {
#pragma unroll
    for (int off = 32; off > 0; off >>= 1) v += __shfl_xor(v, off, 64);
    return v;
}

// ---------------------------------------------------------------------------
// fp32 -> bf16 elementwise convert (weights). n % 4 == 0.
// ---------------------------------------------------------------------------
__global__ __launch_bounds__(256) void convert_bf16_k(const float* __restrict__ in,
                                                      u16* __restrict__ out, int n) {
    int i = (blockIdx.x * 256 + threadIdx.x) * 4;
    if (i >= n) return;
    float4 v = *(const float4*)(in + i);
    ushort4 o = make_ushort4(f2bf(v.x), f2bf(v.y), f2bf(v.z), f2bf(v.w));
    *(ushort4*)(out + i) = o;
}

// ---------------------------------------------------------------------------
// x [B][C][N] fp32 -> xT [B][N][C] bf16.  64x64 tiles via LDS.
// grid = (N/64, C/64, B), block 256.
// ---------------------------------------------------------------------------
__global__ __launch_bounds__(256) void transpose_x(const float* __restrict__ x,
                                                   u16* __restrict__ xT) {
    __shared__ float tile[64][65];
    const int n0 = blockIdx.x * 64;
    const int c0 = blockIdx.y * 64;
    const size_t b = blockIdx.z;
    const float* xb = x + b * (size_t)(C_IN * N_LOC);
    u16* xtb = xT + b * (size_t)(N_LOC * C_IN);
    const int tn = threadIdx.x & 63;
    const int tc = threadIdx.x >> 6;
#pragma unroll
    for (int r = 0; r < 16; ++r) {
        int c = tc + r * 4;
        tile[c][tn] = xb[(size_t)(c0 + c) * N_LOC + n0 + tn];
    }
    __syncthreads();
#pragma unroll
    for (int r = 0; r < 16; ++r) {
        int n = tc + r * 4;
        xtb[(size_t)(n0 + n) * C_IN + c0 + tn] = f2bf(tile[tn][n]);
    }
}

// ---------------------------------------------------------------------------
// bf16 MFMA GEMM:  Out[b][r][c] = act( sum_k Ain[b][r][k] * Wmat[c][k] + bias[c] )
// R = N_LOC = 1024 rows.  Tile 128 x BN, BK=64, 256 threads = 4 waves (2x2).
// m97 structure: global_load_lds w16 staging, 2-barrier K loop, 16x16x32 MFMA.
// grid = (R/128, S/BN, B)
// ---------------------------------------------------------------------------
template <int BN, bool RELU>
__global__ __launch_bounds__(256) void gemm_bf16(const u16* __restrict__ Ain,
                                                 const u16* __restrict__ Wmat,
                                                 const float* __restrict__ bias,
                                                 u16* __restrict__ Out,
                                                 int S, int K) {
    constexpr int WN = BN / 2;
    constexpr int FN = WN / 16;
    __shared__ __align__(16) u16 As[128 * 64];
    __shared__ __align__(16) u16 Bs[BN * 64];
    const int tid = threadIdx.x;
    const int lane = tid & 63;
    const int wv = tid >> 6;
    const int wr = wv >> 1;
    const int wc = wv & 1;
    const int r0 = blockIdx.x * 128;
    const int c0 = blockIdx.y * BN;
    const size_t bb = blockIdx.z;
    const u16* Ab = Ain + bb * (size_t)N_LOC * K + (size_t)r0 * K;
    const u16* Wb = Wmat + (size_t)c0 * K;

    f32x4 acc[4][FN];
#pragma unroll
    for (int mi = 0; mi < 4; ++mi)
#pragma unroll
        for (int ni = 0; ni < FN; ++ni)
            acc[mi][ni] = (f32x4){0.f, 0.f, 0.f, 0.f};

    const int srow = tid >> 3;        // 0..31
    const int scol = (tid & 7) * 8;   // ushort offset in 64-wide row

    const int nk = K / 64;
    for (int kt = 0; kt < nk; ++kt) {
        const int kbase = kt * 64 + scol;
#pragma unroll
        for (int j = 0; j < 4; ++j) {
            int row = j * 32 + srow;
            load_lds16(Ab + (size_t)row * K + kbase, &As[(size_t)(j * 256 + tid) * 8]);
        }
#pragma unroll
        for (int j = 0; j < BN / 32; ++j) {
            int row = j * 32 + srow;
            load_lds16(Wb + (size_t)row * K + kbase, &Bs[(size_t)(j * 256 + tid) * 8]);
        }
        __syncthreads();
#pragma unroll
        for (int kk = 0; kk < 2; ++kk) {
            bf16x8 av[4], bw[FN];
#pragma unroll
            for (int mi = 0; mi < 4; ++mi)
                av[mi] = *(const bf16x8*)&As[(wr * 64 + mi * 16 + (lane & 15)) * 64 +
                                             kk * 32 + (lane >> 4) * 8];
#pragma unroll
            for (int ni = 0; ni < FN; ++ni)
                bw[ni] = *(const bf16x8*)&Bs[(wc * WN + ni * 16 + (lane & 15)) * 64 +
                                             kk * 32 + (lane >> 4) * 8];
#pragma unroll
            for (int mi = 0; mi < 4; ++mi)
#pragma unroll
                for (int ni = 0; ni < FN; ++ni)
                    acc[mi][ni] = __builtin_amdgcn_mfma_f32_16x16x32_bf16(
                        av[mi], bw[ni], acc[mi][ni], 0, 0, 0);
        }
        __syncthreads();
    }

    float bv[FN];
#pragma unroll
    for (int ni = 0; ni < FN; ++ni)
        bv[ni] = bias[c0 + wc * WN + ni * 16 + (lane & 15)];
    u16* Ob = Out + bb * (size_t)N_LOC * S;
#pragma unroll
    for (int mi = 0; mi < 4; ++mi) {
#pragma unroll
        for (int r = 0; r < 4; ++r) {
            int row = r0 + wr * 64 + mi * 16 + (lane >> 4) * 4 + r;
#pragma unroll
            for (int ni = 0; ni < FN; ++ni) {
                int col = c0 + wc * WN + ni * 16 + (lane & 15);
                float v = acc[mi][ni][r] + bv[ni];
                if (RELU) v = fmaxf(v, 0.f);
                Ob[(size_t)row * S + col] = f2bf(v);
            }
        }
    }
}

// ---------------------------------------------------------------------------
// Token MLP (unchanged, fp32).
// ---------------------------------------------------------------------------
__global__ __launch_bounds__(256) void tok_kernel(const float* __restrict__ t,
                                                  const float* __restrict__ tw1,
                                                  const float* __restrict__ tb1,
                                                  const float* __restrict__ tw2,
                                                  const float* __restrict__ tb2,
                                                  float* __restrict__ tok) {
    __shared__ __align__(16) float tl[C_IN];
    __shared__ __align__(16) float hid[HID];
    const int b = blockIdx.x;
    const int tid = threadIdx.x;
    const int lane = tid & 63;
    const int wave = tid >> 6;

    for (int i = tid; i < C_IN; i += 256) tl[i] = t[(size_t)b * C_IN + i];
    __syncthreads();

    for (int j = wave; j < HID; j += 4) {
        const float4* wr = (const float4*)(tw1 + (size_t)j * C_IN);
        const float4* tr = (const float4*)tl;
        float s = 0.f;
#pragma unroll
        for (int q = 0; q < 3; ++q) {
            float4 wv = wr[lane + 64 * q];
            float4 tv = tr[lane + 64 * q];
            s += wv.x * tv.x + wv.y * tv.y + wv.z * tv.z + wv.w * tv.w;
        }
        s = waveReduceSum(s);
        if (lane == 0) hid[j] = fmaxf(s + tb1[j], 0.f);
    }
    __syncthreads();

    for (int g = wave; g < G_DIM; g += 4) {
        const float4* wr = (const float4*)(tw2 + (size_t)g * HID);
        const float4* hr = (const float4*)hid;
        float s = 0.f;
#pragma unroll
        for (int q = 0; q < 2; ++q) {
            float4 wv = wr[lane + 64 * q];
            float4 hv = hr[lane + 64 * q];
            s += wv.x * hv.x + wv.y * hv.y + wv.z * hv.z + wv.w * hv.w;
        }
        s = waveReduceSum(s);
        if (lane == 0) tok[(size_t)b * G_DIM + g] = s + tb2[g];
    }
}

// ---------------------------------------------------------------------------
// Sinkhorn on pT [B][N][M] bf16 -> PT [B][N][M] fp32.
// One block (1024 thr) per batch; thread t owns location (column) t.
// ---------------------------------------------------------------------------
__global__ __launch_bounds__(1024) void sinkhorn_kernel(const u16* __restrict__ pT,
                                                        const float* __restrict__ dust,
                                                        float* __restrict__ PT) {
    __shared__ float u[M_DIM + 1];
    __shared__ float v[N_LOC];
    const int b = blockIdx.x;
    const int t = threadIdx.x;
    const int lane = t & 63;
    const int wave = t >> 6;
    const float alpha = dust[0];
    const float norm = -__logf(1088.f);
    const float logmu_main = norm;
    const float logmu_last = __logf(960.f) + norm;
    const float lognu = norm;
    const u16* pb = pT + (size_t)b * N_LOC * M_DIM;
    const u16* prow = pb + (size_t)t * M_DIM;

    v[t] = 0.f;
    if (t < M_DIM + 1) u[t] = 0.f;
    __syncthreads();

    for (int it = 0; it < 3; ++it) {
        for (int m = wave; m < M_DIM + 1; m += 16) {
            float s = 0.f;
            if (m < M_DIM) {
#pragma unroll
                for (int q = 0; q < 16; ++q) {
                    int c = lane + 64 * q;
                    s += __expf(bf2f(pb[(size_t)c * M_DIM + m]) + v[c]);
                }
            } else {
#pragma unroll
                for (int q = 0; q < 16; ++q) {
                    int c = lane + 64 * q;
                    s += __expf(alpha + v[c]);
                }
            }
            s = waveReduceSum(s);
            if (lane == 0) u[m] = ((m < M_DIM) ? logmu_main : logmu_last) - __logf(s);
        }
        __syncthreads();
        float s = 0.f;
#pragma unroll 8
        for (int m = 0; m < M_DIM; ++m) s += __expf(bf2f(prow[m]) + u[m]);
        s += __expf(alpha + u[M_DIM]);
        v[t] = lognu - __logf(s);
        __syncthreads();
    }

    const float vt = v[t];
    float* Prow = PT + ((size_t)b * N_LOC + t) * M_DIM;
#pragma unroll 8
    for (int m = 0; m < M_DIM; ++m)
        Prow[m] = __expf(bf2f(prow[m]) + u[m] + vt - norm);
}

// ---------------------------------------------------------------------------
// agg[b,l,m] = sum_n fT[b,n,l] * PT[b,n,m].  One block (512 thr) per batch.
// ---------------------------------------------------------------------------
__global__ __launch_bounds__(512) void agg_kernel(const u16* __restrict__ fT,
                                                  const float* __restrict__ PT,
                                                  float* __restrict__ agg) {
    __shared__ __align__(16) float Fs[64][L_DIM];
    __shared__ __align__(16) float Ps[64][M_DIM];
    const int b = blockIdx.x;
    const int tid = threadIdx.x;
    const u16* fb = fT + (size_t)b * N_LOC * L_DIM;
    const float* Pb = PT + (size_t)b * N_LOC * M_DIM;
    const int m0 = (tid & 15) * 4;
    const int l0 = (tid >> 4) * 4;

    float acc[4][4] = {};

    for (int n0 = 0; n0 < N_LOC; n0 += 64) {
        __syncthreads();
#pragma unroll
        for (int pass = 0; pass < 2; ++pass) {
            int idx = pass * 512 + tid;
            int nn = idx >> 4, cc = (idx & 15) * 8;
            const u16* src = fb + (size_t)(n0 + nn) * L_DIM + cc;
            ushort4 h0 = *(const ushort4*)(src);
            ushort4 h1 = *(const ushort4*)(src + 4);
            Fs[nn][cc + 0] = bf2f(h0.x); Fs[nn][cc + 1] = bf2f(h0.y);
            Fs[nn][cc + 2] = bf2f(h0.z); Fs[nn][cc + 3] = bf2f(h0.w);
            Fs[nn][cc + 4] = bf2f(h1.x); Fs[nn][cc + 5] = bf2f(h1.y);
            Fs[nn][cc + 6] = bf2f(h1.z); Fs[nn][cc + 7] = bf2f(h1.w);
        }
#pragma unroll
        for (int pass = 0; pass < 2; ++pass) {
            int idx = pass * 512 + tid;
            int nn = idx >> 4, cc = (idx & 15) * 4;
            float4 vv = *(const float4*)(Pb + (size_t)(n0 + nn) * M_DIM + cc);
            *(float4*)&Ps[nn][cc] = vv;
        }
        __syncthreads();
#pragma unroll 8
        for (int nn = 0; nn < 64; ++nn) {
            float4 a = *(const float4*)(&Fs[nn][l0]);
            float4 bb = *(const float4*)(&Ps[nn][m0]);
            float av[4] = {a.x, a.y, a.z, a.w};
            float bv[4] = {bb.x, bb.y, bb.z, bb.w};
#pragma unroll
            for (int i = 0; i < 4; ++i)
#pragma unroll
                for (int j = 0; j < 4; ++j)
                    acc[i][j] = fmaf(av[i], bv[j], acc[i][j]);
        }
    }

#pragma unroll
    for (int i = 0; i < 4; ++i) {
        float* dst = agg + ((size_t)b * L_DIM + l0 + i) * M_DIM + m0;
        *(float4*)dst = make_float4(acc[i][0], acc[i][1], acc[i][2], acc[i][3]);
    }
}

// ---------------------------------------------------------------------------
// Final normalization cascade (unchanged).
// ---------------------------------------------------------------------------
__global__ __launch_bounds__(256) void final_kernel(const float* __restrict__ agg,
                                                    const float* __restrict__ tok,
                                                    float* __restrict__ out) {
    __shared__ __align__(16) float ag[L_DIM * M_DIM];
    __shared__ float rm[M_DIM];
    __shared__ float red[4];
    __shared__ float tk[G_DIM];
    const int b = blockIdx.x;
    const int tid = threadIdx.x;
    const int lane = tid & 63;
    const int wave = tid >> 6;
    const float EPS = 1e-12f;

    const float4* ab = (const float4*)(agg + (size_t)b * L_DIM * M_DIM);
    for (int e4 = tid; e4 < L_DIM * M_DIM / 4; e4 += 256) ((float4*)ag)[e4] = ab[e4];
    tk[tid] = tok[(size_t)b * G_DIM + tid];
    __syncthreads();

    if (tid < M_DIM) {
        float ss = 0.f;
#pragma unroll 8
        for (int l = 0; l < L_DIM; ++l) {
            float x = ag[l * M_DIM + tid];
            ss = fmaf(x, x, ss);
        }
        rm[tid] = 1.f / fmaxf(sqrtf(ss), EPS);
    }
    const float tv = tk[tid];
    float ssl = tv * tv;
    ssl = waveReduceSum(ssl);
    if (lane == 0) red[wave] = ssl;
    __syncthreads();
    const float stok = red[0] + red[1] + red[2] + red[3];
    const float rt = 1.f / fmaxf(sqrtf(stok), EPS);
    const float tn = tv * rt;

    float gs = tn * tn;
    for (int e = tid; e < L_DIM * M_DIM; e += 256) {
        float x = ag[e] * rm[e & (M_DIM - 1)];
        gs = fmaf(x, x, gs);
    }
    __syncthreads();
    gs = waveReduceSum(gs);
    if (lane == 0) red[wave] = gs;
    __syncthreads();
    const float G = red[0] + red[1] + red[2] + red[3];
    const float rg = 1.f / fmaxf(sqrtf(G), EPS);

    float* ob = out + (size_t)b * (G_DIM + L_DIM * M_DIM);
    ob[tid] = tn * rg;
    for (int e = tid; e < L_DIM * M_DIM; e += 256)
        ob[G_DIM + e] = ag[e] * rm[e & (M_DIM - 1)] * rg;
}

// ---------------------------------------------------------------------------
extern "C" void kernel_launch(void* const* d_in, const int* in_sizes, int n_in,
                              void* d_out, int out_size, void* d_ws, size_t ws_size,
                              hipStream_t stream) {
    const float* x    = (const float*)d_in[0];
    const float* t    = (const float*)d_in[1];
    const float* tw1  = (const float*)d_in[2];
    const float* tb1  = (const float*)d_in[3];
    const float* tw2  = (const float*)d_in[4];
    const float* tb2  = (const float*)d_in[5];
    const float* cw1  = (const float*)d_in[6];
    const float* cb1  = (const float*)d_in[7];
    const float* cw2  = (const float*)d_in[8];
    const float* cb2  = (const float*)d_in[9];
    const float* sw1  = (const float*)d_in[10];
    const float* sb1  = (const float*)d_in[11];
    const float* sw2  = (const float*)d_in[12];
    const float* sb2  = (const float*)d_in[13];
    const float* dust = (const float*)d_in[14];
    float* out = (float*)d_out;

    char* ws = (char*)d_ws;
    // layout (bytes)
    u16* xT    = (u16*)(ws);                         // 100,663,296
    u16* hT    = (u16*)(ws + 100663296ull);          //  67,108,864
    u16* fT    = (u16*)(ws + 167772160ull);          //  16,777,216
    u16* pT    = (u16*)(ws + 184549376ull);          //   8,388,608
    u16* cw1b  = (u16*)(ws + 192937984ull);          //     786,432
    u16* sw1b  = (u16*)(ws + 193724416ull);          //     786,432
    u16* cw2b  = (u16*)(ws + 194510848ull);          //     131,072
    u16* sw2b  = (u16*)(ws + 194641920ull);          //      65,536
    // reuse of xT region after stage-1/2 GEMMs are done:
    float* PT     = (float*)(ws);                    //  16,777,216
    float* tokbuf = (float*)(ws + 20971520ull);      //      65,536
    float* aggbuf = (float*)(ws + 25165824ull);      //   2,097,152

    // 1. weight converts
    convert_bf16_k<<<(HID * C_IN / 4 + 255) / 256, 256, 0, stream>>>(cw1, cw1b, HID * C_IN);
    convert_bf16_k<<<(HID * C_IN / 4 + 255) / 256, 256, 0, stream>>>(sw1, sw1b, HID * C_IN);
    convert_bf16_k<<<(L_DIM * HID / 4 + 255) / 256, 256, 0, stream>>>(cw2, cw2b, L_DIM * HID);
    convert_bf16_k<<<(M_DIM * HID / 4 + 255) / 256, 256, 0, stream>>>(sw2, sw2b, M_DIM * HID);
    // 2. x -> xT (bf16)
    transpose_x<<<dim3(N_LOC / 64, C_IN / 64, B_SZ), 256, 0, stream>>>(x, xT);
    // 3-6. GEMMs
    gemm_bf16<128, true ><<<dim3(8, HID / 128, B_SZ), 256, 0, stream>>>(xT, cw1b, cb1, hT, HID, C_IN);
    gemm_bf16<128, false><<<dim3(8, L_DIM / 128, B_SZ), 256, 0, stream>>>(hT, cw2b, cb2, fT, L_DIM, HID);
    gemm_bf16<128, true ><<<dim3(8, HID / 128, B_SZ), 256, 0, stream>>>(xT, sw1b, sb1, hT, HID, C_IN);
    gemm_bf16<64,  false><<<dim3(8, 1, B_SZ), 256, 0, stream>>>(hT, sw2b, sb2, pT, M_DIM, HID);
    // 7. token MLP
    tok_kernel<<<B_SZ, 256, 0, stream>>>(t, tw1, tb1, tw2, tb2, tokbuf);
    // 8. Sinkhorn (+exp) -> PT (overwrites dead xT region)
    sinkhorn_kernel<<<B_SZ, 1024, 0, stream>>>(pT, dust, PT);
    // 9. VLAD aggregation
    agg_kernel<<<B_SZ, 512, 0, stream>>>(fT, PT, aggbuf);
    // 10. normalization cascade
    final_kernel<<<B_SZ, 256, 0, stream>>>(aggbuf, tokbuf, out);
}

// Round 3
// 351.183 us; speedup vs baseline: 4.6892x; 1.6144x over previous
//
#include <hip/hip_runtime.h>
#include <math.h>

// ---------------------------------------------------------------------------
// SALAD forward, bf16-MFMA, round 3: occupancy fixes for tok/sinkhorn/agg,
// vectorized transpose. GEMM structure unchanged from round 2.
// Layouts: xT[B][N][C], hT[B][N][HID], fT[B][N][L], pT[B][N][M] (bf16);
// PT[B][N][M] fp32.  B=64, C=768, N=1024, HID=512, L=128, M=64, G=256.
// ---------------------------------------------------------------------------

#define B_SZ   64
#define C_IN   768
#define N_LOC  1024
#define HID    512
#define L_DIM  128
#define M_DIM  64
#define G_DIM  256

typedef unsigned short u16;
typedef __bf16 bf16x8 __attribute__((ext_vector_type(8)));
typedef float f32x4 __attribute__((ext_vector_type(4)));

typedef const __attribute__((address_space(1))) void* gptr_t;
typedef __attribute__((address_space(3))) void* sptr_t;

__device__ __forceinline__ void load_lds16(const void* g, void* l) {
    __builtin_amdgcn_global_load_lds((gptr_t)g, (sptr_t)l, 16, 0, 0);
}

__device__ __forceinline__ u16 f2bf(float f) {  // round-to-nearest-even
    unsigned u = __float_as_uint(f);
    u += 0x7fffu + ((u >> 16) & 1u);
    return (u16)(u >> 16);
}
__device__ __forceinline__ float bf2f(u16 h) {
    return __uint_as_float(((unsigned)h) << 16);
}

__device__ __forceinline__ float waveReduceSum(float v) {
#pragma unroll
    for (int off = 32; off > 0; off >>= 1) v += __shfl_xor(v, off, 64);
    return v;
}

// ---------------------------------------------------------------------------
// fp32 -> bf16 elementwise convert (weights). n % 4 == 0.
// ---------------------------------------------------------------------------
__global__ __launch_bounds__(256) void convert_bf16_k(const float* __restrict__ in,
                                                      u16* __restrict__ out, int n) {
    int i = (blockIdx.x * 256 + threadIdx.x) * 4;
    if (i >= n) return;
    float4 v = *(const float4*)(in + i);
    ushort4 o = make_ushort4(f2bf(v.x), f2bf(v.y), f2bf(v.z), f2bf(v.w));
    *(ushort4*)(out + i) = o;
}

// ---------------------------------------------------------------------------
// x [B][C][N] fp32 -> xT [B][N][C] bf16.  64x64 tiles, float4 loads,
// ushort4 coalesced stores. LDS 64x65 fp32 (<=2-way bank aliasing).
// grid = (N/64, C/64, B), block 256.
// ---------------------------------------------------------------------------
__global__ __launch_bounds__(256) void transpose_x(const float* __restrict__ x,
                                                   u16* __restrict__ xT) {
    __shared__ float tile[64][65];
    const int n0 = blockIdx.x * 64;
    const int c0 = blockIdx.y * 64;
    const size_t b = blockIdx.z;
    const float* xb = x + b * (size_t)(C_IN * N_LOC);
    u16* xtb = xT + b * (size_t)(N_LOC * C_IN);
    const int tid = threadIdx.x;

    const int jn = (tid & 15) * 4;   // n offset within tile
    const int cr = tid >> 4;         // 0..15
#pragma unroll
    for (int r = 0; r < 4; ++r) {
        int c = cr + r * 16;
        float4 v = *(const float4*)(xb + (size_t)(c0 + c) * N_LOC + n0 + jn);
        tile[c][jn + 0] = v.x;
        tile[c][jn + 1] = v.y;
        tile[c][jn + 2] = v.z;
        tile[c][jn + 3] = v.w;
    }
    __syncthreads();
    const int c4 = (tid & 15) * 4;   // c offset (consecutive lanes -> consecutive c)
#pragma unroll
    for (int r = 0; r < 4; ++r) {
        int n = (tid >> 4) + r * 16;
        ushort4 o = make_ushort4(f2bf(tile[c4 + 0][n]), f2bf(tile[c4 + 1][n]),
                                 f2bf(tile[c4 + 2][n]), f2bf(tile[c4 + 3][n]));
        *(ushort4*)(xtb + (size_t)(n0 + n) * C_IN + c0 + c4) = o;
    }
}

// ---------------------------------------------------------------------------
// bf16 MFMA GEMM (unchanged round-2 structure).
// Out[b][r][c] = act( sum_k Ain[b][r][k] * Wmat[c][k] + bias[c] )
// grid = (R/128, S/BN, B), 256 threads = 4 waves (2x2).
// ---------------------------------------------------------------------------
template <int BN, bool RELU>
__global__ __launch_bounds__(256) void gemm_bf16(const u16* __restrict__ Ain,
                                                 const u16* __restrict__ Wmat,
                                                 const float* __restrict__ bias,
                                                 u16* __restrict__ Out,
                                                 int S, int K) {
    constexpr int WN = BN / 2;
    constexpr int FN = WN / 16;
    __shared__ __align__(16) u16 As[128 * 64];
    __shared__ __align__(16) u16 Bs[BN * 64];
    const int tid = threadIdx.x;
    const int lane = tid & 63;
    const int wv = tid >> 6;
    const int wr = wv >> 1;
    const int wc = wv & 1;
    const int r0 = blockIdx.x * 128;
    const int c0 = blockIdx.y * BN;
    const size_t bb = blockIdx.z;
    const u16* Ab = Ain + bb * (size_t)N_LOC * K + (size_t)r0 * K;
    const u16* Wb = Wmat + (size_t)c0 * K;

    f32x4 acc[4][FN];
#pragma unroll
    for (int mi = 0; mi < 4; ++mi)
#pragma unroll
        for (int ni = 0; ni < FN; ++ni)
            acc[mi][ni] = (f32x4){0.f, 0.f, 0.f, 0.f};

    const int srow = tid >> 3;        // 0..31
    const int scol = (tid & 7) * 8;   // ushort offset in 64-wide row

    const int nk = K / 64;
    for (int kt = 0; kt < nk; ++kt) {
        const int kbase = kt * 64 + scol;
#pragma unroll
        for (int j = 0; j < 4; ++j) {
            int row = j * 32 + srow;
            load_lds16(Ab + (size_t)row * K + kbase, &As[(size_t)(j * 256 + tid) * 8]);
        }
#pragma unroll
        for (int j = 0; j < BN / 32; ++j) {
            int row = j * 32 + srow;
            load_lds16(Wb + (size_t)row * K + kbase, &Bs[(size_t)(j * 256 + tid) * 8]);
        }
        __syncthreads();
#pragma unroll
        for (int kk = 0; kk < 2; ++kk) {
            bf16x8 av[4], bw[FN];
#pragma unroll
            for (int mi = 0; mi < 4; ++mi)
                av[mi] = *(const bf16x8*)&As[(wr * 64 + mi * 16 + (lane & 15)) * 64 +
                                             kk * 32 + (lane >> 4) * 8];
#pragma unroll
            for (int ni = 0; ni < FN; ++ni)
                bw[ni] = *(const bf16x8*)&Bs[(wc * WN + ni * 16 + (lane & 15)) * 64 +
                                             kk * 32 + (lane >> 4) * 8];
#pragma unroll
            for (int mi = 0; mi < 4; ++mi)
#pragma unroll
                for (int ni = 0; ni < FN; ++ni)
                    acc[mi][ni] = __builtin_amdgcn_mfma_f32_16x16x32_bf16(
                        av[mi], bw[ni], acc[mi][ni], 0, 0, 0);
        }
        __syncthreads();
    }

    float bv[FN];
#pragma unroll
    for (int ni = 0; ni < FN; ++ni)
        bv[ni] = bias[c0 + wc * WN + ni * 16 + (lane & 15)];
    u16* Ob = Out + bb * (size_t)N_LOC * S;
#pragma unroll
    for (int mi = 0; mi < 4; ++mi) {
#pragma unroll
        for (int r = 0; r < 4; ++r) {
            int row = r0 + wr * 64 + mi * 16 + (lane >> 4) * 4 + r;
#pragma unroll
            for (int ni = 0; ni < FN; ++ni) {
                int col = c0 + wc * WN + ni * 16 + (lane & 15);
                float v = acc[mi][ni][r] + bv[ni];
                if (RELU) v = fmaxf(v, 0.f);
                Ob[(size_t)row * S + col] = f2bf(v);
            }
        }
    }
}

// ---------------------------------------------------------------------------
// Token MLP stage 1: hidb[b][j] = relu(t[b] . tw1[j] + tb1[j])
// grid (HID/64, B), 256 thr; wave-per-row, 16 rows/wave.
// ---------------------------------------------------------------------------
__global__ __launch_bounds__(256) void tok1_kernel(const float* __restrict__ t,
                                                   const float* __restrict__ tw1,
                                                   const float* __restrict__ tb1,
                                                   float* __restrict__ hidb) {
    __shared__ __align__(16) float tl[C_IN];
    const int b = blockIdx.y;
    const int j0 = blockIdx.x * 64;
    const int tid = threadIdx.x;
    const int lane = tid & 63;
    const int wave = tid >> 6;
    for (int i = tid; i < C_IN; i += 256) tl[i] = t[(size_t)b * C_IN + i];
    __syncthreads();
    for (int j = wave; j < 64; j += 4) {
        const int row = j0 + j;
        const float4* wr = (const float4*)(tw1 + (size_t)row * C_IN);
        const float4* tr = (const float4*)tl;
        float s = 0.f;
#pragma unroll
        for (int q = 0; q < 3; ++q) {
            float4 wv = wr[lane + 64 * q];
            float4 tv = tr[lane + 64 * q];
            s += wv.x * tv.x + wv.y * tv.y + wv.z * tv.z + wv.w * tv.w;
        }
        s = waveReduceSum(s);
        if (lane == 0) hidb[(size_t)b * HID + row] = fmaxf(s + tb1[row], 0.f);
    }
}

// ---------------------------------------------------------------------------
// Token MLP stage 2: tok[b][g] = hidb[b] . tw2[g] + tb2[g]
// grid (G/64, B), 256 thr.
// ---------------------------------------------------------------------------
__global__ __launch_bounds__(256) void tok2_kernel(const float* __restrict__ hidb,
                                                   const float* __restrict__ tw2,
                                                   const float* __restrict__ tb2,
                                                   float* __restrict__ tok) {
    __shared__ __align__(16) float hl[HID];
    const int b = blockIdx.y;
    const int g0 = blockIdx.x * 64;
    const int tid = threadIdx.x;
    const int lane = tid & 63;
    const int wave = tid >> 6;
    for (int i = tid; i < HID; i += 256) hl[i] = hidb[(size_t)b * HID + i];
    __syncthreads();
    for (int j = wave; j < 64; j += 4) {
        const int row = g0 + j;
        const float4* wr = (const float4*)(tw2 + (size_t)row * HID);
        const float4* hr = (const float4*)hl;
        float s = 0.f;
#pragma unroll
        for (int q = 0; q < 2; ++q) {
            float4 wv = wr[lane + 64 * q];
            float4 hv = hr[lane + 64 * q];
            s += wv.x * hv.x + wv.y * hv.y + wv.z * hv.z + wv.w * hv.w;
        }
        s = waveReduceSum(s);
        if (lane == 0) tok[(size_t)b * G_DIM + row] = s + tb2[row];
    }
}

// ---------------------------------------------------------------------------
// Sinkhorn: pT [B][N][M] bf16 -> PT [B][N][M] fp32.
// One block (1024 thr) per batch. p staged in LDS as sp[m][n] (128 KB):
// row reads (u-update) coalesced, column reads (v-update/output) conflict-free.
// Transpose-on-load: 2-way b16 write aliasing (free).
// ---------------------------------------------------------------------------
__global__ __launch_bounds__(1024) void sinkhorn_kernel(const u16* __restrict__ pT,
                                                        const float* __restrict__ dust,
                                                        float* __restrict__ PT) {
    __shared__ u16 sp[M_DIM][N_LOC];   // 131072 B
    __shared__ float u[M_DIM + 1];
    __shared__ float v[N_LOC];
    const int b = blockIdx.x;
    const int t = threadIdx.x;
    const int lane = t & 63;
    const int wave = t >> 6;
    const float alpha = dust[0];
    const float norm = -__logf(1088.f);
    const float logmu_main = norm;
    const float logmu_last = __logf(960.f) + norm;
    const float lognu = norm;

    // stage: thread t reads its location-row (64 bf16, contiguous) and writes
    // transposed into sp[m][t].
    const uint4* prow = (const uint4*)(pT + ((size_t)b * N_LOC + t) * M_DIM);
#pragma unroll
    for (int q = 0; q < 8; ++q) {
        uint4 ch = prow[q];
        sp[q * 8 + 0][t] = (u16)(ch.x);
        sp[q * 8 + 1][t] = (u16)(ch.x >> 16);
        sp[q * 8 + 2][t] = (u16)(ch.y);
        sp[q * 8 + 3][t] = (u16)(ch.y >> 16);
        sp[q * 8 + 4][t] = (u16)(ch.z);
        sp[q * 8 + 5][t] = (u16)(ch.z >> 16);
        sp[q * 8 + 6][t] = (u16)(ch.w);
        sp[q * 8 + 7][t] = (u16)(ch.w >> 16);
    }
    v[t] = 0.f;
    if (t < M_DIM + 1) u[t] = 0.f;
    __syncthreads();

    for (int it = 0; it < 3; ++it) {
        // u[m] = log_mu[m] - lse_n(Z[m,n] + v[n]); wave w -> rows w, w+16, ...
        for (int m = wave; m < M_DIM + 1; m += 16) {
            float s = 0.f;
            if (m < M_DIM) {
#pragma unroll
                for (int q = 0; q < 16; ++q) {
                    int c = lane + 64 * q;
                    s += __expf(bf2f(sp[m][c]) + v[c]);
                }
            } else {
#pragma unroll
                for (int q = 0; q < 16; ++q) {
                    int c = lane + 64 * q;
                    s += __expf(alpha + v[c]);
                }
            }
            s = waveReduceSum(s);
            if (lane == 0) u[m] = ((m < M_DIM) ? logmu_main : logmu_last) - __logf(s);
        }
        __syncthreads();
        // v[n] = log_nu - lse_m(Z[m,n] + u[m]); thread t owns column t
        float s = 0.f;
#pragma unroll 8
        for (int m = 0; m < M_DIM; ++m) s += __expf(bf2f(sp[m][t]) + u[m]);
        s += __expf(alpha + u[M_DIM]);
        v[t] = lognu - __logf(s);
        __syncthreads();
    }

    const float vt = v[t];
    float* Prow = PT + ((size_t)b * N_LOC + t) * M_DIM;
#pragma unroll
    for (int m4 = 0; m4 < M_DIM; m4 += 4) {
        float4 o;
        o.x = __expf(bf2f(sp[m4 + 0][t]) + u[m4 + 0] + vt - norm);
        o.y = __expf(bf2f(sp[m4 + 1][t]) + u[m4 + 1] + vt - norm);
        o.z = __expf(bf2f(sp[m4 + 2][t]) + u[m4 + 2] + vt - norm);
        o.w = __expf(bf2f(sp[m4 + 3][t]) + u[m4 + 3] + vt - norm);
        *(float4*)(Prow + m4) = o;
    }
}

// ---------------------------------------------------------------------------
// agg[b,l,m] = sum_n fT[b,n,l] * PT[b,n,m].
// grid (L/32, B) = 256 blocks, 256 thr; block tile 32l x 64m; thread 2l x 4m.
// LDS padded (36 / 68 fp32 strides) to rotate banks on staging writes.
// ---------------------------------------------------------------------------
__global__ __launch_bounds__(256) void agg_kernel(const u16* __restrict__ fT,
                                                  const float* __restrict__ PT,
                                                  float* __restrict__ agg) {
    __shared__ float Fs[64][36];
    __shared__ float Ps[64][68];
    const int b = blockIdx.y;
    const int l0 = blockIdx.x * 32;
    const int tid = threadIdx.x;
    const u16* fb = fT + (size_t)b * N_LOC * L_DIM;
    const float* Pb = PT + (size_t)b * N_LOC * M_DIM;

    const int sn = tid >> 2;          // 0..63
    const int flc = (tid & 3) * 8;    // f: 8 l per thread
    const int pmc = (tid & 3) * 16;   // P: 16 m per thread
    const int tl = (tid >> 4) * 2;    // thread l offset (0..30)
    const int tm = (tid & 15) * 4;    // thread m offset (0..60)

    float acc[2][4] = {};

    for (int n0 = 0; n0 < N_LOC; n0 += 64) {
        __syncthreads();
        {
            uint4 ld = *(const uint4*)(fb + (size_t)(n0 + sn) * L_DIM + l0 + flc);
            Fs[sn][flc + 0] = bf2f((u16)(ld.x));
            Fs[sn][flc + 1] = bf2f((u16)(ld.x >> 16));
            Fs[sn][flc + 2] = bf2f((u16)(ld.y));
            Fs[sn][flc + 3] = bf2f((u16)(ld.y >> 16));
            Fs[sn][flc + 4] = bf2f((u16)(ld.z));
            Fs[sn][flc + 5] = bf2f((u16)(ld.z >> 16));
            Fs[sn][flc + 6] = bf2f((u16)(ld.w));
            Fs[sn][flc + 7] = bf2f((u16)(ld.w >> 16));
        }
#pragma unroll
        for (int i = 0; i < 4; ++i) {
            float4 vv = *(const float4*)(Pb + (size_t)(n0 + sn) * M_DIM + pmc + 4 * i);
            *(float4*)&Ps[sn][pmc + 4 * i] = vv;
        }
        __syncthreads();
#pragma unroll 8
        for (int nn = 0; nn < 64; ++nn) {
            float a0 = Fs[nn][tl];
            float a1 = Fs[nn][tl + 1];
            float4 p4 = *(const float4*)&Ps[nn][tm];
            acc[0][0] = fmaf(a0, p4.x, acc[0][0]);
            acc[0][1] = fmaf(a0, p4.y, acc[0][1]);
            acc[0][2] = fmaf(a0, p4.z, acc[0][2]);
            acc[0][3] = fmaf(a0, p4.w, acc[0][3]);
            acc[1][0] = fmaf(a1, p4.x, acc[1][0]);
            acc[1][1] = fmaf(a1, p4.y, acc[1][1]);
            acc[1][2] = fmaf(a1, p4.z, acc[1][2]);
            acc[1][3] = fmaf(a1, p4.w, acc[1][3]);
        }
    }

#pragma unroll
    for (int i = 0; i < 2; ++i) {
        float* dst = agg + ((size_t)b * L_DIM + l0 + tl + i) * M_DIM + tm;
        *(float4*)dst = make_float4(acc[i][0], acc[i][1], acc[i][2], acc[i][3]);
    }
}

// ---------------------------------------------------------------------------
// Final normalization cascade (unchanged).
// ---------------------------------------------------------------------------
__global__ __launch_bounds__(256) void final_kernel(const float* __restrict__ agg,
                                                    const float* __restrict__ tok,
                                                    float* __restrict__ out) {
    __shared__ __align__(16) float ag[L_DIM * M_DIM];
    __shared__ float rm[M_DIM];
    __shared__ float red[4];
    __shared__ float tk[G_DIM];
    const int b = blockIdx.x;
    const int tid = threadIdx.x;
    const int lane = tid & 63;
    const int wave = tid >> 6;
    const float EPS = 1e-12f;

    const float4* ab = (const float4*)(agg + (size_t)b * L_DIM * M_DIM);
    for (int e4 = tid; e4 < L_DIM * M_DIM / 4; e4 += 256) ((float4*)ag)[e4] = ab[e4];
    tk[tid] = tok[(size_t)b * G_DIM + tid];
    __syncthreads();

    if (tid < M_DIM) {
        float ss = 0.f;
#pragma unroll 8
        for (int l = 0; l < L_DIM; ++l) {
            float x = ag[l * M_DIM + tid];
            ss = fmaf(x, x, ss);
        }
        rm[tid] = 1.f / fmaxf(sqrtf(ss), EPS);
    }
    const float tv = tk[tid];
    float ssl = tv * tv;
    ssl = waveReduceSum(ssl);
    if (lane == 0) red[wave] = ssl;
    __syncthreads();
    const float stok = red[0] + red[1] + red[2] + red[3];
    const float rt = 1.f / fmaxf(sqrtf(stok), EPS);
    const float tn = tv * rt;

    float gs = tn * tn;
    for (int e = tid; e < L_DIM * M_DIM; e += 256) {
        float x = ag[e] * rm[e & (M_DIM - 1)];
        gs = fmaf(x, x, gs);
    }
    __syncthreads();
    gs = waveReduceSum(gs);
    if (lane == 0) red[wave] = gs;
    __syncthreads();
    const float G = red[0] + red[1] + red[2] + red[3];
    const float rg = 1.f / fmaxf(sqrtf(G), EPS);

    float* ob = out + (size_t)b * (G_DIM + L_DIM * M_DIM);
    ob[tid] = tn * rg;
    for (int e = tid; e < L_DIM * M_DIM; e += 256)
        ob[G_DIM + e] = ag[e] * rm[e & (M_DIM - 1)] * rg;
}

// ---------------------------------------------------------------------------
extern "C" void kernel_launch(void* const* d_in, const int* in_sizes, int n_in,
                              void* d_out, int out_size, void* d_ws, size_t ws_size,
                              hipStream_t stream) {
    const float* x    = (const float*)d_in[0];
    const float* t    = (const float*)d_in[1];
    const float* tw1  = (const float*)d_in[2];
    const float* tb1  = (const float*)d_in[3];
    const float* tw2  = (const float*)d_in[4];
    const float* tb2  = (const float*)d_in[5];
    const float* cw1  = (const float*)d_in[6];
    const float* cb1  = (const float*)d_in[7];
    const float* cw2  = (const float*)d_in[8];
    const float* cb2  = (const float*)d_in[9];
    const float* sw1  = (const float*)d_in[10];
    const float* sb1  = (const float*)d_in[11];
    const float* sw2  = (const float*)d_in[12];
    const float* sb2  = (const float*)d_in[13];
    const float* dust = (const float*)d_in[14];
    float* out = (float*)d_out;

    char* ws = (char*)d_ws;
    u16* xT    = (u16*)(ws);                         // 100,663,296
    u16* hT    = (u16*)(ws + 100663296ull);          //  67,108,864
    u16* fT    = (u16*)(ws + 167772160ull);          //  16,777,216
    u16* pT    = (u16*)(ws + 184549376ull);          //   8,388,608
    u16* cw1b  = (u16*)(ws + 192937984ull);          //     786,432
    u16* sw1b  = (u16*)(ws + 193724416ull);          //     786,432
    u16* cw2b  = (u16*)(ws + 194510848ull);          //     131,072
    u16* sw2b  = (u16*)(ws + 194641920ull);          //      65,536
    float* hidb = (float*)(ws + 194707456ull);       //     131,072
    // reuse of dead xT region:
    float* PT     = (float*)(ws);                    //  16,777,216
    float* tokbuf = (float*)(ws + 20971520ull);      //      65,536
    float* aggbuf = (float*)(ws + 25165824ull);      //   2,097,152

    convert_bf16_k<<<(HID * C_IN / 4 + 255) / 256, 256, 0, stream>>>(cw1, cw1b, HID * C_IN);
    convert_bf16_k<<<(HID * C_IN / 4 + 255) / 256, 256, 0, stream>>>(sw1, sw1b, HID * C_IN);
    convert_bf16_k<<<(L_DIM * HID / 4 + 255) / 256, 256, 0, stream>>>(cw2, cw2b, L_DIM * HID);
    convert_bf16_k<<<(M_DIM * HID / 4 + 255) / 256, 256, 0, stream>>>(sw2, sw2b, M_DIM * HID);
    transpose_x<<<dim3(N_LOC / 64, C_IN / 64, B_SZ), 256, 0, stream>>>(x, xT);

    gemm_bf16<128, true ><<<dim3(8, HID / 128, B_SZ), 256, 0, stream>>>(xT, cw1b, cb1, hT, HID, C_IN);
    gemm_bf16<128, false><<<dim3(8, L_DIM / 128, B_SZ), 256, 0, stream>>>(hT, cw2b, cb2, fT, L_DIM, HID);
    gemm_bf16<128, true ><<<dim3(8, HID / 128, B_SZ), 256, 0, stream>>>(xT, sw1b, sb1, hT, HID, C_IN);
    gemm_bf16<64,  false><<<dim3(8, 1, B_SZ), 256, 0, stream>>>(hT, sw2b, sb2, pT, M_DIM, HID);

    tok1_kernel<<<dim3(HID / 64, B_SZ), 256, 0, stream>>>(t, tw1, tb1, hidb);
    tok2_kernel<<<dim3(G_DIM / 64, B_SZ), 256, 0, stream>>>(hidb, tw2, tb2, tokbuf);

    sinkhorn_kernel<<<B_SZ, 1024, 0, stream>>>(pT, dust, PT);
    agg_kernel<<<dim3(L_DIM / 32, B_SZ), 256, 0, stream>>>(fT, PT, aggbuf);
    final_kernel<<<B_SZ, 256, 0, stream>>>(aggbuf, tokbuf, out);
}